// Round 6
// baseline (102.473 us; speedup 1.0000x reference)
//
#include <hip/hip_runtime.h>
#include <cstddef>

#define NN 4096   // nodes
#define NL 8      // layers
#define ND 128    // feature dim

#define SRC_BLOCKS (NL * (NN / 256))   // 128 src blocks, dispatched FIRST
#define ROWS 4                         // deg rows per block (1 wave / row)

#define CHUNK 128                      // j's per fused-out block
#define BATCH 16                       // distinct-src GEMVs per batch

typedef int   int4v   __attribute__((ext_vector_type(4)));
typedef float float4v __attribute__((ext_vector_type(4)));

// ws layout (fully rewritten every call -> no zeroing needed):
//   deg : [NL*NN] f32 @ 0        (128 KB)
//   src : [NL*NN] i32 @ 131072   (128 KB)

// ---------------------------------------------------------------------------
// Fused: blocks [0,128) compute src (latency-bound, hides under the BW-bound
// deg stream); remaining blocks do deg row sums, 4 rows/block, one wave per
// row (wave-reduce only, no LDS), non-temporal int4 loads.
// ---------------------------------------------------------------------------
__global__ __launch_bounds__(256) void degsrc_kernel(const int* __restrict__ adj,
                                                     float* __restrict__ deg,
                                                     int* __restrict__ src) {
  if (blockIdx.x < SRC_BLOCKS) {
    // ---- src[l*NN+j] = max( largest i>j with adj[l,i,j]!=0 , j ) ----
    const int bid = blockIdx.x;
    const int l = bid >> 4;                    // 16 blocks per layer
    const int j = ((bid & 15) << 8) + threadIdx.x;
    const int* __restrict__ A = adj + (size_t)l * NN * NN + j;
    int cur = j;
    bool found = false;
    int itop = NN - 1;
    while (true) {
      int ibot = itop - 31;
      if (ibot < 0) ibot = 0;
      int best = -1;
#pragma unroll
      for (int k = 0; k < 32; ++k) {
        int i = itop - k;
        int a = (i >= ibot) ? A[(size_t)i * NN] : 0;
        int c = (a != 0 && i > j) ? i : -1;
        if (c > best) best = c;
      }
      if (!found && best >= 0) { cur = best; found = true; }
      bool done = found || (ibot <= j + 1);
      if (__syncthreads_and((int)done)) break;
      itop = ibot - 1;
    }
    src[l * NN + j] = cur;
  } else {
    // ---- deg[row] = sum(adj row) + 1 ; ROWS rows/block, 1 wave per row ----
    const size_t row = (size_t)(blockIdx.x - SRC_BLOCKS) * ROWS +
                       (threadIdx.x >> 6);
    const int lane = threadIdx.x & 63;
    const int4v* __restrict__ p =
        reinterpret_cast<const int4v*>(adj + row * (size_t)NN);
    int s = 0;
#pragma unroll
    for (int k = 0; k < 16; ++k) {
      int4v v = __builtin_nontemporal_load(&p[lane + k * 64]);
      s += v.x + v.y + v.z + v.w;
    }
    for (int off = 32; off > 0; off >>= 1) s += __shfl_down(s, off, 64);
    if (lane == 0) deg[row] = (float)s + 1.0f;
  }
}

// ---------------------------------------------------------------------------
// Fused tail: per block (128 j's of one layer):
//   1. gather src/deg for the chunk, build distinct-src bitmask in LDS
//   2. compact set bits -> list (LDS prefix scan; deterministic)
//   3. per batch of <=16 distinct srcs: stage feature rows in LDS, GEMV with
//      W held in REGISTERS (thread t owns W row t&127; fb reads are LDS
//      broadcasts -> no LDS BW bottleneck), write scaled rows NT to out.
// Expected ~8-10 distinct srcs per chunk (random p=0.5) -> 1 batch; degrades
// gracefully to 8 batches worst case.
// ---------------------------------------------------------------------------
__global__ __launch_bounds__(256) void outfused_kernel(
    const float* __restrict__ feature, const float* __restrict__ W,
    const float* __restrict__ deg, const int* __restrict__ src,
    float* __restrict__ out) {
  __shared__ unsigned mask[NN / 32];   // 128 words
  __shared__ int ps[128];
  __shared__ int list[CHUNK];
  __shared__ int srcs[CHUNK];
  __shared__ float scj[CHUNK];
  __shared__ int smap[CHUNK];
  __shared__ float fb[BATCH][ND];
  __shared__ float wf[BATCH][ND];

  const int t = threadIdx.x;
  const int l = blockIdx.y;
  const int jbase = blockIdx.x * CHUNK;

  // W row into registers (L2-hot after first blocks; reused across all slots)
  const int d = t & 127;
  float4v wreg[32];
#pragma unroll
  for (int q = 0; q < 32; ++q)
    wreg[q] = reinterpret_cast<const float4v*>(W)[(size_t)d * 32 + q];

  // -- phase A: chunk src/deg gather + bitmask --
  if (t < 128) mask[t] = 0u;
  __syncthreads();
  if (t < CHUNK) {
    int j = jbase + t;
    int s = src[l * NN + j];
    srcs[t] = s;
    atomicOr(&mask[s >> 5], 1u << (s & 31));
    scj[t] = rsqrtf(deg[l * NN + s] * deg[l * NN + j]);
  }
  __syncthreads();

  // -- phase B: compact set bits (prefix scan over 128 word popcounts) --
  int pc = 0;
  if (t < 128) { pc = __popc(mask[t]); ps[t] = pc; }
  __syncthreads();
  for (int off = 1; off < 128; off <<= 1) {
    int v = 0;
    if (t < 128 && t >= off) v = ps[t - off];
    __syncthreads();
    if (t < 128 && t >= off) ps[t] += v;
    __syncthreads();
  }
  if (t < 128) {
    unsigned m = mask[t];
    int pos = ps[t] - pc;
    while (m) {
      int b = __ffs(m) - 1;
      m &= m - 1;
      list[pos++] = (t << 5) | b;
    }
  }
  __syncthreads();
  const int cnt = ps[127];

  const int h = t >> 7;   // half: which 8 slots this thread computes

  for (int b0 = 0; b0 < cnt; b0 += BATCH) {
    const int nb = min(BATCH, cnt - b0);
    __syncthreads();   // previous batch's wf/smap readers done

    // stage feature rows for this batch (coalesced float4)
    for (int idx = t; idx < nb * 32; idx += 256) {
      int k = idx >> 5, q = idx & 31;
      int i = list[b0 + k];
      reinterpret_cast<float4v*>(fb[k])[q] =
          reinterpret_cast<const float4v*>(feature + ((size_t)i * NL + l) * ND)[q];
    }
    // slot map for this batch
    if (t < CHUNK) {
      int s = srcs[t], sl = -1;
      for (int k = 0; k < nb; ++k)
        if (list[b0 + k] == s) sl = k;
      smap[t] = sl;
    }
    __syncthreads();

    // GEMV: wf[k][d] = sum_e W[d,e] * fb[k][e]; fb reads are broadcasts
    const int kend = min(h * 8 + 8, nb);
    for (int k = h * 8; k < kend; ++k) {
      float acc = 0.0f;
#pragma unroll
      for (int q = 0; q < 32; ++q) {
        float4v f = reinterpret_cast<const float4v*>(fb[k])[q];
        acc += wreg[q].x * f.x + wreg[q].y * f.y + wreg[q].z * f.z +
               wreg[q].w * f.w;
      }
      wf[k][d] = acc;
    }
    __syncthreads();

    // write out rows whose src is in this batch (NT float4, coalesced)
    for (int r0 = 0; r0 < CHUNK; r0 += 8) {
      const int r = r0 + (t >> 5);
      const int q = t & 31;
      const int sl = smap[r];
      if (sl >= 0) {
        float4v v = reinterpret_cast<const float4v*>(wf[sl])[q];
        const float sc = scj[r];
        v.x *= sc; v.y *= sc; v.z *= sc; v.w *= sc;
        __builtin_nontemporal_store(
            v, reinterpret_cast<float4v*>(out) +
                   ((size_t)(jbase + r) * NL + l) * 32 + q);
      }
    }
  }
}

// ---------------------------------------------------------------------------
extern "C" void kernel_launch(void* const* d_in, const int* in_sizes, int n_in,
                              void* d_out, int out_size, void* d_ws,
                              size_t ws_size, hipStream_t stream) {
  const float* feature = (const float*)d_in[0];   // [NN, NL, ND] f32
  const float* W       = (const float*)d_in[1];   // [ND, ND]     f32
  const int*   adj     = (const int*)d_in[2];     // [NL, NN, NN] i32
  float* out = (float*)d_out;                     // [NN, NL, ND] f32

  char* ws = (char*)d_ws;
  float* deg = (float*)(ws);
  int*   src = (int*)(ws + 131072);

  degsrc_kernel<<<SRC_BLOCKS + NL * NN / ROWS, 256, 0, stream>>>(adj, deg, src);
  outfused_kernel<<<dim3(NN / CHUNK, NL), 256, 0, stream>>>(feature, W, deg,
                                                            src, out);
}